// Round 2
// baseline (796.218 us; speedup 1.0000x reference)
//
#include <hip/hip_runtime.h>
#include <stdint.h>

// SparseMoE on gfx950. Round 1 resubmit (R1 was a broker timeout, no data).
// - Router h via 4-term bf16-split GEMM (fp32-accurate scores -> top-2 matches np ref)
// - Sparse expert dispatch (gather 4096 slots), bf16 MFMA expert GEMMs
// - ws usage ~92.4 MB
typedef unsigned short ushort_t;
typedef __attribute__((ext_vector_type(8))) short short8;
typedef __attribute__((ext_vector_type(4))) float f32x4;

#define EMBED   1024
#define DFF     4096
#define NEXP    8
#define TOKENS  2048
#define SLOTS   4096   // TOKENS * TOP_K

__device__ __forceinline__ ushort_t f2bf(float f) {
  unsigned u = __float_as_uint(f);
  u += 0x7FFFu + ((u >> 16) & 1u);   // RNE
  return (ushort_t)(u >> 16);
}
__device__ __forceinline__ float bf2f(ushort_t b) {
  return __uint_as_float(((unsigned)b) << 16);
}
__device__ __forceinline__ ushort_t to_bf(float v)    { return f2bf(v); }
__device__ __forceinline__ ushort_t to_bf(ushort_t v) { return v; }

__global__ void zero_small(int* counts, int* cursors) {
  int i = threadIdx.x;
  if (i < NEXP) { counts[i] = 0; cursors[i] = 0; }
}

// x [2048,1024] fp32 -> Xs [2048,4096] bf16 cols [xh | xl | xh | xl]
__global__ void split_x(const float* __restrict__ x, ushort_t* __restrict__ Xs) {
  int t = blockIdx.x;
  int d = threadIdx.x * 4;
  float4 v = *(const float4*)(x + (size_t)t * EMBED + d);
  ushort4 hi, lo;
  hi.x = f2bf(v.x); lo.x = f2bf(v.x - bf2f(hi.x));
  hi.y = f2bf(v.y); lo.y = f2bf(v.y - bf2f(hi.y));
  hi.z = f2bf(v.z); lo.z = f2bf(v.z - bf2f(hi.z));
  hi.w = f2bf(v.w); lo.w = f2bf(v.w - bf2f(hi.w));
  ushort_t* row = Xs + (size_t)t * 4096;
  *(ushort4*)(row + d)        = hi;
  *(ushort4*)(row + 1024 + d) = lo;
  *(ushort4*)(row + 2048 + d) = hi;
  *(ushort4*)(row + 3072 + d) = lo;
}

// rw1 [1024,4096] fp32 -> RW1s [4096,4096] bf16 rows [wh; wh; wl; wl]
__global__ void split_rw1(const float* __restrict__ rw1, ushort_t* __restrict__ RW1s) {
  int k = blockIdx.x;                 // 0..4095
  int src = k & 1023;
  bool hipart = (k < 2048);
  const float* srow = rw1 + (size_t)src * DFF;
  ushort_t* drow = RW1s + (size_t)k * DFF;
  #pragma unroll
  for (int i = 0; i < 4; i++) {
    int n = (threadIdx.x + i * 256) * 4;
    float4 v = *(const float4*)(srow + n);
    ushort4 o;
    if (hipart) {
      o.x = f2bf(v.x); o.y = f2bf(v.y); o.z = f2bf(v.z); o.w = f2bf(v.w);
    } else {
      o.x = f2bf(v.x - bf2f(f2bf(v.x)));
      o.y = f2bf(v.y - bf2f(f2bf(v.y)));
      o.z = f2bf(v.z - bf2f(f2bf(v.z)));
      o.w = f2bf(v.w - bf2f(f2bf(v.w)));
    }
    *(ushort4*)(drow + n) = o;
  }
}

// Generic bf16 MFMA GEMM: C[M,N] = epilogue(A[M,K](bf16) @ B[K,N](TB) + bias)
// 128x128 tile, BK=32, 4 waves (2x2), 4x4 16x16x32 MFMAs per wave.
// B is convert(+transpose)-staged into LDS [n][k], stride 40 (pad) -> all
// ds accesses are b128 at the bank-traffic floor.
// EXPERT mode: blockIdx.z = expert; A rows are slots [off[e], off[e+1]).
template<bool EXPERT, typename TB, bool OUT_BF16, bool RELU, bool GATE>
__global__ __launch_bounds__(256, 2)
void gemm_kernel(const ushort_t* __restrict__ A, const TB* __restrict__ B,
                 const float* __restrict__ bias, void* __restrict__ Cout,
                 const float* __restrict__ slot_gate, const int* __restrict__ off,
                 int M, int N, int K)
{
  __shared__ ushort_t As[128 * 40];
  __shared__ ushort_t Bs[128 * 40];

  int m_base = 0, m_cnt = M;
  const TB* Bp = B;
  const float* biasp = bias;
  if (EXPERT) {
    int e = blockIdx.z;
    m_base = off[e];
    m_cnt  = off[e + 1] - m_base;
    Bp     = B + (size_t)e * K * N;
    biasp  = bias + (size_t)e * N;
  }
  const int row0 = blockIdx.y * 128;
  if (row0 >= m_cnt) return;     // uniform early-exit before any barrier
  const int col0 = blockIdx.x * 128;

  const int tid  = threadIdx.x;
  const int lane = tid & 63;
  const int wid  = tid >> 6;
  const int wm = wid & 1, wn = wid >> 1;

  f32x4 acc[4][4];
  #pragma unroll
  for (int i = 0; i < 4; i++)
    #pragma unroll
    for (int j = 0; j < 4; j++)
      acc[i][j] = (f32x4){0.f, 0.f, 0.f, 0.f};

  const int ar  = tid >> 2;            // A stage: 0..63 (row), 2 iters
  const int ac  = (tid & 3) << 3;      // A stage: k-chunk 0,8,16,24
  const int bn  = tid & 127;           // B stage: col n
  const int bc0 = (tid >> 7) << 1;     // B stage: chunk 0 or 2

  const int rowA = lane & 15;
  const int qk   = (lane >> 4) << 3;

  const int nktiles = K >> 5;
  for (int kt = 0; kt < nktiles; kt++) {
    const int k0 = kt << 5;
    __syncthreads();
    // ---- A tile: 128x32 bf16, row-major stride 40
    #pragma unroll
    for (int hh = 0; hh < 2; hh++) {
      int rr = ar + hh * 64;
      int rg = m_base + min(row0 + rr, m_cnt - 1);   // clamp: OOB rows discarded later
      uint4 v = *(const uint4*)(A + (size_t)rg * K + k0 + ac);
      *(uint4*)(As + rr * 40 + ac) = v;
    }
    // ---- B tile: 32x128 TB -> LDS transposed [n][k], stride 40
    #pragma unroll
    for (int ci = 0; ci < 2; ci++) {
      int c = bc0 + ci;
      union { ushort_t u[8]; uint4 v; } pk;
      #pragma unroll
      for (int j = 0; j < 8; j++) {
        int kk = k0 + c * 8 + j;
        pk.u[j] = to_bf(Bp[(size_t)kk * N + col0 + bn]);   // coalesced per j
      }
      *(uint4*)(Bs + bn * 40 + c * 8) = pk.v;
    }
    __syncthreads();

    short8 af[4], bfr[4];
    #pragma unroll
    for (int i = 0; i < 4; i++) {
      af[i]  = *(const short8*)(As + (wm * 64 + i * 16 + rowA) * 40 + qk);
      bfr[i] = *(const short8*)(Bs + (wn * 64 + i * 16 + rowA) * 40 + qk);
    }
    #pragma unroll
    for (int mt = 0; mt < 4; mt++)
      #pragma unroll
      for (int nt = 0; nt < 4; nt++)
        acc[mt][nt] = __builtin_amdgcn_mfma_f32_16x16x32_bf16(af[mt], bfr[nt], acc[mt][nt], 0, 0, 0);
  }

  // ---- epilogue. C/D layout (m89-verified): col=lane&15, row=(lane>>4)*4+i
  float bv[4];
  #pragma unroll
  for (int nt = 0; nt < 4; nt++)
    bv[nt] = biasp[col0 + wn * 64 + nt * 16 + (lane & 15)];

  #pragma unroll
  for (int mt = 0; mt < 4; mt++) {
    #pragma unroll
    for (int i = 0; i < 4; i++) {
      int r_loc = row0 + wm * 64 + mt * 16 + ((lane >> 4) << 2) + i;
      if (r_loc < m_cnt) {
        size_t rowo = (size_t)(m_base + r_loc) * N;
        float g = 1.f;
        if (GATE) g = slot_gate[m_base + r_loc];
        #pragma unroll
        for (int nt = 0; nt < 4; nt++) {
          float v = acc[mt][nt][i] + bv[nt];
          if (RELU) v = fmaxf(v, 0.f);
          if (GATE) v *= g;
          int c = col0 + wn * 64 + nt * 16 + (lane & 15);
          if (OUT_BF16) ((ushort_t*)Cout)[rowo + c] = f2bf(v);
          else          ((float*)Cout)[rowo + c]   = v;
        }
      }
    }
  }
}

// score = h @ rw2 + rb2 (fp32), then top-2 + softmax gates + expert counts.
__global__ void router_score(const float* __restrict__ h, const float* __restrict__ rw2,
                             const float* __restrict__ rb2, int* __restrict__ topi,
                             float* __restrict__ gates, int* __restrict__ counts)
{
  int t = blockIdx.x * 4 + (threadIdx.x >> 6);
  if (t >= TOKENS) return;
  int lane = threadIdx.x & 63;
  const float* hr = h + (size_t)t * DFF;
  float acc[8] = {0,0,0,0,0,0,0,0};
  for (int j = lane; j < DFF; j += 64) {
    float hv = hr[j];
    const float4* w = (const float4*)(rw2 + (size_t)j * 8);
    float4 w0 = w[0], w1 = w[1];
    acc[0] += hv * w0.x; acc[1] += hv * w0.y; acc[2] += hv * w0.z; acc[3] += hv * w0.w;
    acc[4] += hv * w1.x; acc[5] += hv * w1.y; acc[6] += hv * w1.z; acc[7] += hv * w1.w;
  }
  #pragma unroll
  for (int e = 0; e < 8; e++)
    for (int o = 32; o > 0; o >>= 1)
      acc[e] += __shfl_down(acc[e], o);
  if (lane == 0) {
    float s[8];
    #pragma unroll
    for (int e = 0; e < 8; e++) s[e] = acc[e] + rb2[e];
    int i0 = 0;
    #pragma unroll
    for (int e = 1; e < 8; e++) if (s[e] > s[i0]) i0 = e;   // ties -> lower idx (jax)
    int i1 = (i0 == 0) ? 1 : 0;
    #pragma unroll
    for (int e = 0; e < 8; e++) if (e != i0 && s[e] > s[i1]) i1 = e;
    float ex = __expf(s[i1] - s[i0]);           // <= 1
    float g0 = 1.f / (1.f + ex);
    float g1 = ex / (1.f + ex);
    topi[t * 2] = i0; topi[t * 2 + 1] = i1;
    gates[t * 2] = g0; gates[t * 2 + 1] = g1;
    atomicAdd(&counts[i0], 1);
    atomicAdd(&counts[i1], 1);
  }
}

__global__ void prefix_off(const int* __restrict__ counts, int* __restrict__ off) {
  if (threadIdx.x == 0) {
    int a = 0;
    for (int e = 0; e < NEXP; e++) { off[e] = a; a += counts[e]; }
    off[NEXP] = a;   // == SLOTS
  }
}

__global__ void assign_slots(const int* __restrict__ topi, const float* __restrict__ gates,
                             const int* __restrict__ off, int* __restrict__ cursors,
                             int* __restrict__ slot_token, float* __restrict__ slot_gate,
                             int* __restrict__ tok_slot)
{
  int t = blockIdx.x * blockDim.x + threadIdx.x;
  if (t >= TOKENS) return;
  #pragma unroll
  for (int k = 0; k < 2; k++) {
    int e = topi[t * 2 + k];
    int p = atomicAdd(&cursors[e], 1);
    int s = off[e] + p;
    slot_token[s] = t;
    slot_gate[s]  = gates[t * 2 + k];
    tok_slot[t * 2 + k] = s;
  }
}

__global__ void gather_x(const float* __restrict__ x, const int* __restrict__ slot_token,
                         ushort_t* __restrict__ Xg)
{
  int s = blockIdx.x;
  int t = slot_token[s];
  int d = threadIdx.x * 4;
  float4 v = *(const float4*)(x + (size_t)t * EMBED + d);
  ushort4 o;
  o.x = f2bf(v.x); o.y = f2bf(v.y); o.z = f2bf(v.z); o.w = f2bf(v.w);
  *(ushort4*)(Xg + (size_t)s * EMBED + d) = o;
}

__global__ void combine_out(const float* __restrict__ Ys, const int* __restrict__ tok_slot,
                            float* __restrict__ out)
{
  int t = blockIdx.x;
  int d = threadIdx.x * 4;
  int s0 = tok_slot[t * 2], s1 = tok_slot[t * 2 + 1];
  float4 a = *(const float4*)(Ys + (size_t)s0 * EMBED + d);
  float4 b = *(const float4*)(Ys + (size_t)s1 * EMBED + d);
  float4 o; o.x = a.x + b.x; o.y = a.y + b.y; o.z = a.z + b.z; o.w = a.w + b.w;
  *(float4*)(out + (size_t)t * EMBED + d) = o;
}

extern "C" void kernel_launch(void* const* d_in, const int* in_sizes, int n_in,
                              void* d_out, int out_size, void* d_ws, size_t ws_size,
                              hipStream_t stream)
{
  const float* x   = (const float*)d_in[0];
  const float* rw1 = (const float*)d_in[1];
  const float* rb1 = (const float*)d_in[2];
  const float* rw2 = (const float*)d_in[3];
  const float* rb2 = (const float*)d_in[4];
  const float* W1  = (const float*)d_in[5];
  const float* b1  = (const float*)d_in[6];
  const float* W2  = (const float*)d_in[7];
  const float* b2  = (const float*)d_in[8];
  float* out = (float*)d_out;

  // ws carve (all 256-aligned). Total ~92.4 MB.
  char* p = (char*)d_ws;
  ushort_t* RW1s = (ushort_t*)p;  p += (size_t)4096 * 4096 * 2;            // 33.55 MB
  ushort_t* Xs   = (ushort_t*)p;                                           // [2048,4096] bf16
  float*    Ys   = (float*)Xs;    p += (size_t)2048 * 4096 * 2;            // 16.78 MB (reused: Ys [4096,1024] f32)
  float*    h    = (float*)p;                                              // [2048,4096] f32
  ushort_t* Hs   = (ushort_t*)h;  p += (size_t)2048 * 4096 * 4;            // 33.55 MB (reused: Hs [4096,4096] bf16)
  ushort_t* Xg   = (ushort_t*)p;  p += (size_t)4096 * 1024 * 2;            // 8.39 MB
  int*   topi       = (int*)p;    p += 2048 * 2 * 4;
  float* gates      = (float*)p;  p += 2048 * 2 * 4;
  int*   tok_slot   = (int*)p;    p += 2048 * 2 * 4;
  int*   slot_token = (int*)p;    p += 4096 * 4;
  float* slot_gate  = (float*)p;  p += 4096 * 4;
  int*   counts     = (int*)p;    p += 256;
  int*   cursors    = (int*)p;    p += 256;
  int*   off        = (int*)p;    p += 256;

  zero_small<<<1, 64, 0, stream>>>(counts, cursors);
  split_x  <<<2048, 256, 0, stream>>>(x, Xs);
  split_rw1<<<4096, 256, 0, stream>>>(rw1, RW1s);

  // Router GEMM1 (split-bf16, K=4096): h = relu(x @ rw1 + rb1), fp32 out
  gemm_kernel<false, ushort_t, false, true, false>
      <<<dim3(32, 16, 1), 256, 0, stream>>>(Xs, RW1s, rb1, h, nullptr, nullptr, 2048, DFF, 4096);

  router_score<<<512, 256, 0, stream>>>(h, rw2, rb2, topi, gates, counts);
  prefix_off  <<<1, 64, 0, stream>>>(counts, off);
  assign_slots<<<8, 256, 0, stream>>>(topi, gates, off, cursors, slot_token, slot_gate, tok_slot);
  gather_x    <<<4096, 256, 0, stream>>>(x, slot_token, Xg);

  // Expert GEMM1: Hs = relu(Xg @ W1[e] + b1[e]), bf16 out
  gemm_kernel<true, float, true, true, false>
      <<<dim3(32, 16, 8), 256, 0, stream>>>(Xg, W1, b1, Hs, nullptr, off, 0, DFF, EMBED);
  // Expert GEMM2: Ys = gate * (Hs @ W2[e] + b2[e]), fp32 out
  gemm_kernel<true, float, false, false, true>
      <<<dim3(8, 16, 8), 256, 0, stream>>>(Hs, W2, b2, Ys, slot_gate, off, 0, EMBED, DFF);

  combine_out<<<2048, 256, 0, stream>>>(Ys, tok_slot, out);
}

// Round 3
// 666.771 us; speedup vs baseline: 1.1941x; 1.1941x over previous
//
#include <hip/hip_runtime.h>
#include <stdint.h>

// SparseMoE gfx950, Round 3: async global_load_lds staging + XOR-swizzled LDS,
// K-split GEMM2 with atomic-out epilogue, 3-term router split (K=3072),
// ws-size-adaptive weight pre-transpose (layout A >=109.2MB, else B'').
typedef unsigned short ushort_t;
typedef __attribute__((ext_vector_type(8))) short short8;
typedef __attribute__((ext_vector_type(4))) float f32x4;

#define EMBED   1024
#define DFF     4096
#define NEXP    8
#define TOKENS  2048
#define SLOTS   4096

__device__ __forceinline__ ushort_t f2bf(float f) {
  unsigned u = __float_as_uint(f);
  u += 0x7FFFu + ((u >> 16) & 1u);   // RNE
  return (ushort_t)(u >> 16);
}
__device__ __forceinline__ float bf2f(ushort_t b) {
  return __uint_as_float(((unsigned)b) << 16);
}

// async 16B/lane global->LDS DMA. LDS dest wave-uniform; lane i lands at +16*i.
__device__ __forceinline__ void gl2lds16(const void* g, void* l) {
  typedef const __attribute__((address_space(1))) unsigned char* gp_t;
  typedef __attribute__((address_space(3))) unsigned char* lp_t;
  __builtin_amdgcn_global_load_lds((gp_t)(uintptr_t)g, (lp_t)(uintptr_t)l, 16, 0, 0);
}

__global__ void zero_small(int* counts, int* cursors) {
  int i = threadIdx.x;
  if (i < NEXP) { counts[i] = 0; cursors[i] = 0; }
}

// x [2048,1024] f32 -> Xs3 [2048,3072] bf16 : [xh | xl | xh]
__global__ void split_x3(const float* __restrict__ x, ushort_t* __restrict__ Xs) {
  int t = blockIdx.x;
  int d = threadIdx.x * 4;
  float4 v = *(const float4*)(x + (size_t)t * EMBED + d);
  ushort4 hi, lo;
  hi.x = f2bf(v.x); lo.x = f2bf(v.x - bf2f(hi.x));
  hi.y = f2bf(v.y); lo.y = f2bf(v.y - bf2f(hi.y));
  hi.z = f2bf(v.z); lo.z = f2bf(v.z - bf2f(hi.z));
  hi.w = f2bf(v.w); lo.w = f2bf(v.w - bf2f(hi.w));
  ushort_t* row = Xs + (size_t)t * 3072;
  *(ushort4*)(row + d)        = hi;
  *(ushort4*)(row + 1024 + d) = lo;
  *(ushort4*)(row + 2048 + d) = hi;
}

// transpose+convert: dst[n][dst_koff+k] = bf16( src[k][n] )  (lo: bf16 residual)
// src fp32 [64k x 64n] tile per block. grid: (N/64, K/64, E)
__global__ void transp_conv(const float* __restrict__ src, ushort_t* __restrict__ dst,
                            int src_ld, int dst_ld, long src_estride, long dst_estride,
                            int dst_koff, int lo)
{
  __shared__ float t[64][65];
  const float* s = src + (size_t)blockIdx.z * src_estride;
  ushort_t* d = dst + (size_t)blockIdx.z * dst_estride;
  int n0 = blockIdx.x * 64, k0 = blockIdx.y * 64;
  int tid = threadIdx.x;
  int kk = tid >> 4, nn = (tid & 15) * 4;
  #pragma unroll
  for (int it = 0; it < 4; it++) {
    float4 v = *(const float4*)(s + (size_t)(k0 + kk + it * 16) * src_ld + n0 + nn);
    t[kk + it * 16][nn]     = v.x;
    t[kk + it * 16][nn + 1] = v.y;
    t[kk + it * 16][nn + 2] = v.z;
    t[kk + it * 16][nn + 3] = v.w;
  }
  __syncthreads();
  int nn2 = tid >> 3, kk2 = (tid & 7) * 8;
  #pragma unroll
  for (int it = 0; it < 2; it++) {
    int n = nn2 + it * 32;
    union { ushort_t u[8]; uint4 v; } pk;
    #pragma unroll
    for (int j = 0; j < 8; j++) {
      float xv = t[kk2 + j][n];
      ushort_t hv = f2bf(xv);
      pk.u[j] = lo ? f2bf(xv - bf2f(hv)) : hv;
    }
    *(uint4*)(d + (size_t)(n0 + n) * dst_ld + dst_koff + k0 + kk2) = pk.v;
  }
}

// ---------------- MFMA GEMM ----------------
// 128x128 tile, BK=32, 4 waves 2x2, 4x4 mfma_16x16x32_bf16.
// LDS tiles 128x32 ushort UNPADDED, chunk-XOR swizzle: slot(q,row)=q^((row>>1)&3)
//   -> global_load_lds linear writes; fragment reads 2-way/phase = conflict-free.
// BPATH 0: B pre-transposed bf16 [n][k] via async DMA. 1: B fp32 [k][n], staged transpose.
// OUTMODE 0: f32 store. 1: bf16 store. 2: atomicAdd(out[token][c], gate*(v)) with
//   bias added only on K-chunk 0.
template<int BPATH, int OUTMODE, bool RELU, bool EXPERT, int SPLITK>
__global__ __launch_bounds__(256, 4)
void gemm_kernel(const ushort_t* __restrict__ A, const void* __restrict__ Bv,
                 const float* __restrict__ bias, void* __restrict__ Cout,
                 const float* __restrict__ slot_gate, const int* __restrict__ slot_token,
                 const int* __restrict__ off, int M, int N, int K)
{
  __shared__ ushort_t As[128 * 32];
  __shared__ ushort_t Bs[128 * 32];

  int e = 0, kc = 0;
  if (EXPERT) { e = blockIdx.z / SPLITK; kc = blockIdx.z % SPLITK; }
  int m_base = 0, m_cnt = M;
  if (EXPERT) { m_base = off[e]; m_cnt = off[e + 1] - m_base; }
  const int row0 = blockIdx.y * 128;
  if (row0 >= m_cnt) return;                 // uniform exit before barriers
  const int col0 = blockIdx.x * 128;
  const int Kc   = K / SPLITK;
  const int kbeg = kc * Kc;

  const int tid  = threadIdx.x;
  const int lane = tid & 63;
  const int wid  = tid >> 6;
  const int wm = wid & 1, wn = wid >> 1;

  // staging lane constants (DMA): lane i -> tile row base+ (i>>2), slot i&3,
  // fetched global chunk = (i&3) ^ ((i>>3)&3)
  const int srow  = lane >> 2;
  const int schk8 = ((lane & 3) ^ ((lane >> 3) & 3)) * 8;

  const ushort_t* gA[2];
  ushort_t *ldsA[2], *ldsB[2];
  #pragma unroll
  for (int h = 0; h < 2; h++) {
    int r  = row0 + h * 64 + wid * 16 + srow;
    int rg = m_base + min(r, m_cnt - 1);     // clamp; OOB rows discarded in epilogue
    gA[h]   = A + (size_t)rg * K + kbeg + schk8;
    ldsA[h] = As + (h * 64 + wid * 16) * 32;
    ldsB[h] = Bs + (h * 64 + wid * 16) * 32;
  }
  const ushort_t* gB[2] = {nullptr, nullptr};
  const float* Bf = nullptr;
  if constexpr (BPATH == 0) {
    const ushort_t* Bt = (const ushort_t*)Bv + (EXPERT ? (size_t)e * N * K : 0);
    #pragma unroll
    for (int h = 0; h < 2; h++) {
      int n = col0 + h * 64 + wid * 16 + srow;
      gB[h] = Bt + (size_t)n * K + kbeg + schk8;
    }
  } else {
    Bf = (const float*)Bv + (EXPERT ? (size_t)e * (size_t)K * N : 0);
  }
  const int bn  = tid & 127;          // BPATH=1 staging col
  const int bc0 = (tid >> 7) << 1;    // BPATH=1 chunk pair

  f32x4 acc[4][4];
  #pragma unroll
  for (int i = 0; i < 4; i++)
    #pragma unroll
    for (int j = 0; j < 4; j++)
      acc[i][j] = (f32x4){0.f, 0.f, 0.f, 0.f};

  // fragment read constants
  const int q  = lane >> 4;
  const int rr = lane & 15;
  const int sw8 = (q ^ ((rr >> 1) & 3)) * 8;
  const int abase = (wm * 64 + rr) * 32 + sw8;
  const int bbase = (wn * 64 + rr) * 32 + sw8;

  const int nkt = Kc >> 5;
  for (int kt = 0; kt < nkt; kt++) {
    const int k0 = kt << 5;
    __syncthreads();
    #pragma unroll
    for (int h = 0; h < 2; h++) gl2lds16(gA[h] + k0, ldsA[h]);
    if constexpr (BPATH == 0) {
      #pragma unroll
      for (int h = 0; h < 2; h++) gl2lds16(gB[h] + k0, ldsB[h]);
    } else {
      #pragma unroll
      for (int ci = 0; ci < 2; ci++) {
        int c = bc0 + ci;
        union { ushort_t u[8]; uint4 v; } pk;
        #pragma unroll
        for (int j = 0; j < 8; j++)
          pk.u[j] = f2bf(Bf[(size_t)(kbeg + k0 + c * 8 + j) * N + col0 + bn]);
        int s = c ^ ((bn >> 1) & 3);
        *(uint4*)(Bs + bn * 32 + s * 8) = pk.v;
      }
    }
    __syncthreads();

    short8 af[4], bfr[4];
    #pragma unroll
    for (int i = 0; i < 4; i++) {
      af[i]  = *(const short8*)(As + abase + i * 512);
      bfr[i] = *(const short8*)(Bs + bbase + i * 512);
    }
    #pragma unroll
    for (int mt = 0; mt < 4; mt++)
      #pragma unroll
      for (int nt = 0; nt < 4; nt++)
        acc[mt][nt] = __builtin_amdgcn_mfma_f32_16x16x32_bf16(af[mt], bfr[nt], acc[mt][nt], 0, 0, 0);
  }

  // epilogue. C/D layout: col=lane&15, row=(lane>>4)*4+i  (m89-verified)
  const float* biasp = bias + (EXPERT ? (size_t)e * N : 0);
  float bv[4];
  #pragma unroll
  for (int nt = 0; nt < 4; nt++)
    bv[nt] = biasp[col0 + wn * 64 + nt * 16 + rr];
  const float bscale = (SPLITK == 1 || kc == 0) ? 1.f : 0.f;

  #pragma unroll
  for (int mt = 0; mt < 4; mt++) {
    #pragma unroll
    for (int i = 0; i < 4; i++) {
      int r_loc = row0 + wm * 64 + mt * 16 + q * 4 + i;
      if (r_loc < m_cnt) {
        int slot = m_base + r_loc;
        float g = 1.f; int tok = 0;
        if (OUTMODE == 2) { g = slot_gate[slot]; tok = slot_token[slot]; }
        #pragma unroll
        for (int nt = 0; nt < 4; nt++) {
          float v = acc[mt][nt][i] + bscale * bv[nt];
          if (RELU) v = fmaxf(v, 0.f);
          int c = col0 + wn * 64 + nt * 16 + rr;
          if (OUTMODE == 0)      ((float*)Cout)[(size_t)slot * N + c]    = v;
          else if (OUTMODE == 1) ((ushort_t*)Cout)[(size_t)slot * N + c] = f2bf(v);
          else atomicAdd(&((float*)Cout)[(size_t)tok * N + c], g * v);
        }
      }
    }
  }
}

// score = h @ rw2 + rb2 (fp32), then top-2 + softmax gates + expert counts.
__global__ void router_score(const float* __restrict__ h, const float* __restrict__ rw2,
                             const float* __restrict__ rb2, int* __restrict__ topi,
                             float* __restrict__ gates, int* __restrict__ counts)
{
  int t = blockIdx.x * 4 + (threadIdx.x >> 6);
  if (t >= TOKENS) return;
  int lane = threadIdx.x & 63;
  const float* hr = h + (size_t)t * DFF;
  float acc[8] = {0,0,0,0,0,0,0,0};
  for (int j = lane; j < DFF; j += 64) {
    float hv = hr[j];
    const float4* w = (const float4*)(rw2 + (size_t)j * 8);
    float4 w0 = w[0], w1 = w[1];
    acc[0] += hv * w0.x; acc[1] += hv * w0.y; acc[2] += hv * w0.z; acc[3] += hv * w0.w;
    acc[4] += hv * w1.x; acc[5] += hv * w1.y; acc[6] += hv * w1.z; acc[7] += hv * w1.w;
  }
  #pragma unroll
  for (int e = 0; e < 8; e++)
    for (int o = 32; o > 0; o >>= 1)
      acc[e] += __shfl_down(acc[e], o);
  if (lane == 0) {
    float s[8];
    #pragma unroll
    for (int e = 0; e < 8; e++) s[e] = acc[e] + rb2[e];
    int i0 = 0;
    #pragma unroll
    for (int e = 1; e < 8; e++) if (s[e] > s[i0]) i0 = e;   // ties -> lower idx (jax)
    int i1 = (i0 == 0) ? 1 : 0;
    #pragma unroll
    for (int e = 0; e < 8; e++) if (e != i0 && s[e] > s[i1]) i1 = e;
    float ex = __expf(s[i1] - s[i0]);
    float g0 = 1.f / (1.f + ex);
    float g1 = ex / (1.f + ex);
    topi[t * 2] = i0; topi[t * 2 + 1] = i1;
    gates[t * 2] = g0; gates[t * 2 + 1] = g1;
    atomicAdd(&counts[i0], 1);
    atomicAdd(&counts[i1], 1);
  }
}

__global__ void prefix_off(const int* __restrict__ counts, int* __restrict__ off) {
  if (threadIdx.x == 0) {
    int a = 0;
    for (int e = 0; e < NEXP; e++) { off[e] = a; a += counts[e]; }
    off[NEXP] = a;
  }
}

__global__ void assign_slots(const int* __restrict__ topi, const float* __restrict__ gates,
                             const int* __restrict__ off, int* __restrict__ cursors,
                             int* __restrict__ slot_token, float* __restrict__ slot_gate)
{
  int t = blockIdx.x * blockDim.x + threadIdx.x;
  if (t >= TOKENS) return;
  #pragma unroll
  for (int k = 0; k < 2; k++) {
    int e = topi[t * 2 + k];
    int p = atomicAdd(&cursors[e], 1);
    int s = off[e] + p;
    slot_token[s] = t;
    slot_gate[s]  = gates[t * 2 + k];
  }
}

__global__ void gather_x(const float* __restrict__ x, const int* __restrict__ slot_token,
                         ushort_t* __restrict__ Xg)
{
  int s = blockIdx.x;
  int t = slot_token[s];
  int d = threadIdx.x * 4;
  float4 v = *(const float4*)(x + (size_t)t * EMBED + d);
  ushort4 o;
  o.x = f2bf(v.x); o.y = f2bf(v.y); o.z = f2bf(v.z); o.w = f2bf(v.w);
  *(ushort4*)(Xg + (size_t)s * EMBED + d) = o;
}

extern "C" void kernel_launch(void* const* d_in, const int* in_sizes, int n_in,
                              void* d_out, int out_size, void* d_ws, size_t ws_size,
                              hipStream_t stream)
{
  const float* x   = (const float*)d_in[0];
  const float* rw1 = (const float*)d_in[1];
  const float* rb1 = (const float*)d_in[2];
  const float* rw2 = (const float*)d_in[3];
  const float* rb2 = (const float*)d_in[4];
  const float* W1  = (const float*)d_in[5];
  const float* b1  = (const float*)d_in[6];
  const float* W2  = (const float*)d_in[7];
  const float* b2  = (const float*)d_in[8];
  float* out = (float*)d_out;
  char* ws = (char*)d_ws;

  // Layout A (needs 109.2MB): [Wt 67.1MB: RW1t+Xs3 early, W1t then W2t later][Xg][Hs/h][small]
  // Layout B'' (79.8MB, ws>=92.4 proven by R2): [RW1t][Xs3][Xg][Hs/h][small]; expert B fp32-staged.
  const size_t SZ_RW1T = (size_t)4096 * 3072 * 2;   // 25,165,824
  const size_t SZ_XS3  = (size_t)2048 * 3072 * 2;   // 12,582,912
  const size_t SZ_WT   = (size_t)NEXP * 4096 * 1024 * 2; // 67,108,864
  const size_t SZ_XG   = (size_t)SLOTS * EMBED * 2; //  8,388,608
  const size_t SZ_H    = (size_t)SLOTS * DFF * 2;   // 33,554,432 (= 2048*4096*4 fp32 h)
  const size_t SZ_SMALL = 131072;
  const size_t NEED_A  = SZ_WT + SZ_XG + SZ_H + SZ_SMALL;   // 109,182,976
  const bool layoutA = (ws_size >= NEED_A);

  ushort_t *RW1t, *Xs3, *Wt, *Xg, *Hs;
  char* ps;
  if (layoutA) {
    Wt   = (ushort_t*)ws;                 // W1t, later W2t (aliases RW1t+Xs3)
    RW1t = (ushort_t*)ws;
    Xs3  = (ushort_t*)(ws + SZ_RW1T);
    Xg   = (ushort_t*)(ws + SZ_WT);
    Hs   = (ushort_t*)(ws + SZ_WT + SZ_XG);
    ps   = ws + SZ_WT + SZ_XG + SZ_H;
  } else {
    Wt   = nullptr;
    RW1t = (ushort_t*)ws;
    Xs3  = (ushort_t*)(ws + SZ_RW1T);
    Xg   = (ushort_t*)(ws + SZ_RW1T + SZ_XS3);
    Hs   = (ushort_t*)(ws + SZ_RW1T + SZ_XS3 + SZ_XG);
    ps   = ws + SZ_RW1T + SZ_XS3 + SZ_XG + SZ_H;
  }
  float* h = (float*)Hs;                  // h aliases Hs (disjoint lifetimes)
  int*   topi       = (int*)ps;    ps += TOKENS * 2 * 4;
  float* gates      = (float*)ps;  ps += TOKENS * 2 * 4;
  int*   slot_token = (int*)ps;    ps += SLOTS * 4;
  float* slot_gate  = (float*)ps;  ps += SLOTS * 4;
  int*   counts     = (int*)ps;    ps += 256;
  int*   cursors    = (int*)ps;    ps += 256;
  int*   off        = (int*)ps;    ps += 256;

  hipMemsetAsync(d_out, 0, (size_t)TOKENS * EMBED * 4, stream);
  zero_small<<<1, 64, 0, stream>>>(counts, cursors);
  split_x3<<<TOKENS, 256, 0, stream>>>(x, Xs3);

  // RW1t [n=4096][k'=3072] = [wh | wh | wl] transposed from rw1 [1024][4096]
  transp_conv<<<dim3(64, 16, 1), 256, 0, stream>>>(rw1, RW1t, DFF, 3072, 0, 0, 0,    0);
  transp_conv<<<dim3(64, 16, 1), 256, 0, stream>>>(rw1, RW1t, DFF, 3072, 0, 0, 1024, 0);
  transp_conv<<<dim3(64, 16, 1), 256, 0, stream>>>(rw1, RW1t, DFF, 3072, 0, 0, 2048, 1);

  // Router: h = relu(Xs3 @ RW1t^T + rb1), fp32, K=3072
  gemm_kernel<0, 0, true, false, 1>
      <<<dim3(32, 16, 1), 256, 0, stream>>>(Xs3, RW1t, rb1, h,
                                            nullptr, nullptr, nullptr, TOKENS, DFF, 3072);
  router_score<<<512, 256, 0, stream>>>(h, rw2, rb2, topi, gates, counts);
  prefix_off  <<<1, 64, 0, stream>>>(counts, off);
  assign_slots<<<8, 256, 0, stream>>>(topi, gates, off, cursors, slot_token, slot_gate);
  gather_x    <<<SLOTS, 256, 0, stream>>>(x, slot_token, Xg);

  if (layoutA) {
    // W1t [e][n=4096][k=1024] (over RW1t+Xs3, both dead)
    transp_conv<<<dim3(64, 16, NEXP), 256, 0, stream>>>(
        W1, Wt, DFF, EMBED, (long)EMBED * DFF, (long)DFF * EMBED, 0, 0);
    gemm_kernel<0, 1, true, true, 1>
        <<<dim3(32, 32, NEXP), 256, 0, stream>>>(Xg, Wt, b1, Hs,
                                                 nullptr, nullptr, off, 0, DFF, EMBED);
    // W2t [e][n=1024][k=4096] (over W1t, dead after GEMM1)
    transp_conv<<<dim3(16, 64, NEXP), 256, 0, stream>>>(
        W2, Wt, EMBED, DFF, (long)DFF * EMBED, (long)EMBED * DFF, 0, 0);
    gemm_kernel<0, 2, false, true, 4>
        <<<dim3(8, 32, NEXP * 4), 256, 0, stream>>>(Hs, Wt, b2, out,
                                                    slot_gate, slot_token, off, 0, EMBED, DFF);
  } else {
    gemm_kernel<1, 1, true, true, 1>
        <<<dim3(32, 32, NEXP), 256, 0, stream>>>(Xg, W1, b1, Hs,
                                                 nullptr, nullptr, off, 0, DFF, EMBED);
    gemm_kernel<1, 2, false, true, 4>
        <<<dim3(8, 32, NEXP * 4), 256, 0, stream>>>(Hs, W2, b2, out,
                                                    slot_gate, slot_token, off, 0, EMBED, DFF);
  }
}